// Round 4
// baseline (115.005 us; speedup 1.0000x reference)
//
#include <hip/hip_runtime.h>
#include <hip/hip_bf16.h>
#include <math.h>

// x[32,512,64,64] f32; w1[32,512] f32; w2[512,32] f32.
// Bit-replication of the presumed numpy-fp32 reference pipeline:
//   y = np.mean(x,(2,3))           -> numpy pairwise_sum (128-blocks, unroll-8, tree)
//   h = relu(np.einsum('bc,rc->br')) -> SSE sum-of-products (mod-4 lanes, (L0+L1)+(L2+L3))
//   s = 1/(1+np.exp(-z))           -> correctly-rounded fp32 exp via fp64, fp32 add/div
//   idx = argsort(-s, stable)[:, :256]; out = take_along_axis(x, idx)
// All fp32 ops via __f*_rn intrinsics to forbid FMA contraction / reassociation.

#define C1 512
#define C2 256
#define CMID 32
#define HW 4096   // 64*64
#define B 32

__device__ float g_y[B * C1];     // pooled means, fp32 (numpy-bit-exact)
__device__ int   g_idx[B * C2];   // top-256 channel indices per batch

// ---------------- Kernel 1: numpy-pairwise mean ----------------
// pairwise_sum(4096): recursive halving to 32 blocks of 128; each 128-block:
// r[j] = a[j]; for i=1..15: r[j] += a[8i+j]; res = ((r0+r1)+(r2+r3))+((r4+r5)+(r6+r7)).
// Tree over blocks = perfect binary tree in index order. mean = sum / 4096.0f.
__global__ __launch_bounds__(256) void pool_np_kernel(const float* __restrict__ x) {
    int bc = blockIdx.x;                        // 0 .. B*C1-1
    const float* a = x + (size_t)bc * HW;
    int t = threadIdx.x;                        // 0..255
    int w = t >> 6;                             // wave 0..3
    int L = t & 63;
    int g = L >> 3;                             // 8-group -> 128-block w*8+g
    int j = L & 7;                              // accumulator index r_j
    const float* base = a + (w * 8 + g) * 128;
    float r = base[j];
    for (int i = 1; i < 16; ++i)
        r = __fadd_rn(r, base[8 * i + j]);
    // ((r0+r1)+(r2+r3))+((r4+r5)+(r6+r7)) via xor-shuffles (fp32 add is
    // bitwise-commutative, so every lane holds the canonical-tree bits)
    r = __fadd_rn(r, __shfl_xor(r, 1));
    r = __fadd_rn(r, __shfl_xor(r, 2));
    r = __fadd_rn(r, __shfl_xor(r, 4));
    __shared__ float bs[32];
    if (j == 0) bs[w * 8 + g] = r;
    __syncthreads();
    if (t == 0) {
        float s1[16], s2[8], s3[4], s4[2];
        for (int i = 0; i < 16; ++i) s1[i] = __fadd_rn(bs[2*i],  bs[2*i+1]);
        for (int i = 0; i < 8;  ++i) s2[i] = __fadd_rn(s1[2*i],  s1[2*i+1]);
        for (int i = 0; i < 4;  ++i) s3[i] = __fadd_rn(s2[2*i],  s2[2*i+1]);
        for (int i = 0; i < 2;  ++i) s4[i] = __fadd_rn(s3[2*i],  s3[2*i+1]);
        float tot = __fadd_rn(s4[0], s4[1]);
        g_y[bc] = __fdiv_rn(tot, 4096.0f);
    }
}

// numpy einsum SSE sum_of_products_contig_two: single __m128 accumulator;
// per 8-chunk: acc += p[0:4]; acc += p[4:8]; final (L0+L1)+(L2+L3).
__device__ __forceinline__ float dot_sse(const float* __restrict__ u,
                                         const float* __restrict__ v, int n) {
    float L0 = 0.f, L1 = 0.f, L2 = 0.f, L3 = 0.f;
    for (int c = 0; c < n; c += 8) {
        L0 = __fadd_rn(L0, __fmul_rn(u[c+0], v[c+0]));
        L1 = __fadd_rn(L1, __fmul_rn(u[c+1], v[c+1]));
        L2 = __fadd_rn(L2, __fmul_rn(u[c+2], v[c+2]));
        L3 = __fadd_rn(L3, __fmul_rn(u[c+3], v[c+3]));
        L0 = __fadd_rn(L0, __fmul_rn(u[c+4], v[c+4]));
        L1 = __fadd_rn(L1, __fmul_rn(u[c+5], v[c+5]));
        L2 = __fadd_rn(L2, __fmul_rn(u[c+6], v[c+6]));
        L3 = __fadd_rn(L3, __fmul_rn(u[c+7], v[c+7]));
    }
    return __fadd_rn(__fadd_rn(L0, L1), __fadd_rn(L2, L3));
}

// ---------------- Kernel 2: SE MLP (fp32 numpy-replica) + stable rank ----------------
__global__ __launch_bounds__(512) void se_np_kernel(const float* __restrict__ w1,
                                                    const float* __restrict__ w2) {
    int b = blockIdx.x;        // 0..31
    int t = threadIdx.x;       // 0..511
    __shared__ float ys[C1];
    __shared__ float hs[CMID];
    __shared__ float ss[C1];

    ys[t] = g_y[b * C1 + t];
    __syncthreads();

    if (t < CMID) {
        float z = dot_sse(ys, w1 + t * C1, C1);
        hs[t] = z > 0.0f ? z : 0.0f;           // np.maximum(z, 0)
    }
    __syncthreads();

    {
        float z = dot_sse(hs, w2 + t * CMID, CMID);
        // sigmoid: fp32 1/(1+exp(-z)); exp correctly rounded via fp64
        float e = (float)exp((double)(-z));
        ss[t] = __fdiv_rn(1.0f, __fadd_rn(1.0f, e));
    }
    __syncthreads();

    // stable argsort(-s): rank = #{s' > s} + #{equal with smaller index}
    float sc = ss[t];
    int rank = 0;
    for (int c = 0; c < C1; ++c) {
        float v = ss[c];
        rank += (int)((v > sc) || (v == sc && c < t));
    }
    if (rank < C2) g_idx[b * C2 + rank] = t;
}

// ---------------- Kernel 3: per-batch channel gather (plane copy) ----------------
__global__ __launch_bounds__(256) void gather_kernel(const float* __restrict__ x,
                                                     float* __restrict__ out) {
    int bid = blockIdx.x;                      // b*C2 + r
    int b = bid >> 8;
    int c = g_idx[bid];
    const float4* src = (const float4*)(x + ((size_t)(b * C1 + c)) * HW);
    float4* dst = (float4*)(out + (size_t)bid * HW);
    int t = threadIdx.x;
#pragma unroll
    for (int k = 0; k < 4; ++k)
        dst[k * 256 + t] = src[k * 256 + t];
}

extern "C" void kernel_launch(void* const* d_in, const int* in_sizes, int n_in,
                              void* d_out, int out_size, void* d_ws, size_t ws_size,
                              hipStream_t stream) {
    const float* x  = (const float*)d_in[0];
    const float* w1 = (const float*)d_in[1];
    const float* w2 = (const float*)d_in[2];
    float* out = (float*)d_out;

    pool_np_kernel<<<B * C1, 256, 0, stream>>>(x);
    se_np_kernel<<<B, C1, 0, stream>>>(w1, w2);
    gather_kernel<<<B * C2, 256, 0, stream>>>(x, out);
}

// Round 5
// 109.681 us; speedup vs baseline: 1.0485x; 1.0485x over previous
//
#include <hip/hip_runtime.h>
#include <hip/hip_bf16.h>
#include <math.h>

// x[32,512,64,64] f32; w1[32,512] f32; w2[512,32] f32.
// Bit-replication of the numpy-fp32 reference pipeline (round-4 PASSED, absmax 0.0):
//   y = np.mean(x,(2,3))             -> numpy pairwise_sum (128-blocks, 8 accums, tree)
//   h = relu(np.einsum('bc,rc->br')) -> SSE sum-of-products (mod-4 lanes, (L0+L1)+(L2+L3))
//   s = 1/(1+np.exp(-z))             -> correctly-rounded fp32 exp via fp64, fp32 add/div
//   idx = argsort(-s, stable)[:, :256]; out = take_along_axis(x, idx)
// This round: perf only. Pool rewritten as one-wave-per-channel with float4 loads
// (numpy's 8 accumulators = two float4 chains, per-component adds identical),
// shuffle-only combine trees (fp32 add bitwise-commutative -> canonical bits in
// every lane). Layer-1 dots parallelized 4x over numpy's independent SSE chains.

#define C1 512
#define C2 256
#define CMID 32
#define HW 4096   // 64*64
#define B 32

__device__ float g_y[B * C1];     // pooled means, fp32 (numpy-bit-exact)
__device__ int   g_idx[B * C2];   // top-256 channel indices per batch

// ---------------- Kernel 1: numpy-pairwise mean, one wave per channel ----------------
// 128-block m = L>>1, half l = L&1 owns accumulators r[4l..4l+3] as a float4.
// Chain per accumulator j: r_j = a[j]; r_j += a[8i+j], i=1..15  (exact numpy order).
// Combine: lane0 (r0+r1)+(r2+r3), lane1 (r4+r5)+(r6+r7), xor1 -> block sum;
// xor2,4,8,16,32 -> perfect binary tree over the 32 blocks (= numpy recursion).
__global__ __launch_bounds__(256) void pool_np_kernel(const float* __restrict__ x) {
    int bc = blockIdx.x * 4 + (threadIdx.x >> 6);   // channel 0..16383
    int L = threadIdx.x & 63;
    const float* a = x + (size_t)bc * HW;
    const float* base = a + (L >> 1) * 128 + (L & 1) * 4;
    float4 r = *(const float4*)base;
#pragma unroll
    for (int i = 1; i < 16; ++i) {
        float4 v = *(const float4*)(base + 8 * i);
        r.x = __fadd_rn(r.x, v.x);
        r.y = __fadd_rn(r.y, v.y);
        r.z = __fadd_rn(r.z, v.z);
        r.w = __fadd_rn(r.w, v.w);
    }
    float s = __fadd_rn(__fadd_rn(r.x, r.y), __fadd_rn(r.z, r.w));
    s = __fadd_rn(s, __shfl_xor(s, 1));    // block sum (s_low + s_high)
    s = __fadd_rn(s, __shfl_xor(s, 2));    // tree over blocks
    s = __fadd_rn(s, __shfl_xor(s, 4));
    s = __fadd_rn(s, __shfl_xor(s, 8));
    s = __fadd_rn(s, __shfl_xor(s, 16));
    s = __fadd_rn(s, __shfl_xor(s, 32));
    if (L == 0) g_y[bc] = __fdiv_rn(s, 4096.0f);
}

// numpy einsum SSE sum_of_products_contig_two: single __m128 accumulator;
// per 8-chunk: acc += p[0:4]; acc += p[4:8]; final (L0+L1)+(L2+L3).
__device__ __forceinline__ float dot_sse(const float* __restrict__ u,
                                         const float* __restrict__ v, int n) {
    float L0 = 0.f, L1 = 0.f, L2 = 0.f, L3 = 0.f;
    for (int c = 0; c < n; c += 8) {
        L0 = __fadd_rn(L0, __fmul_rn(u[c+0], v[c+0]));
        L1 = __fadd_rn(L1, __fmul_rn(u[c+1], v[c+1]));
        L2 = __fadd_rn(L2, __fmul_rn(u[c+2], v[c+2]));
        L3 = __fadd_rn(L3, __fmul_rn(u[c+3], v[c+3]));
        L0 = __fadd_rn(L0, __fmul_rn(u[c+4], v[c+4]));
        L1 = __fadd_rn(L1, __fmul_rn(u[c+5], v[c+5]));
        L2 = __fadd_rn(L2, __fmul_rn(u[c+6], v[c+6]));
        L3 = __fadd_rn(L3, __fmul_rn(u[c+7], v[c+7]));
    }
    return __fadd_rn(__fadd_rn(L0, L1), __fadd_rn(L2, L3));
}

// ---------------- Kernel 2: SE MLP (fp32 numpy-replica) + stable rank ----------------
__global__ __launch_bounds__(512) void se_np_kernel(const float* __restrict__ w1,
                                                    const float* __restrict__ w2) {
    int b = blockIdx.x;        // 0..31
    int t = threadIdx.x;       // 0..511
    __shared__ float ys[C1];
    __shared__ float hs[CMID];
    __shared__ float ss[C1];

    ys[t] = g_y[b * C1 + t];
    __syncthreads();

    // Layer 1: 32 rows x 4 independent SSE chains (numpy L0..L3), thread = (row,k)
    if (t < CMID * 4) {
        int row = t >> 2, k = t & 3;
        const float* v = w1 + row * C1;
        float Lk = 0.f;
        for (int c = 0; c < C1; c += 8) {
            Lk = __fadd_rn(Lk, __fmul_rn(ys[c + k],     v[c + k]));
            Lk = __fadd_rn(Lk, __fmul_rn(ys[c + 4 + k], v[c + 4 + k]));
        }
        // (L0+L1)+(L2+L3): xor1 then xor2 (bitwise-commutative adds)
        Lk = __fadd_rn(Lk, __shfl_xor(Lk, 1));
        Lk = __fadd_rn(Lk, __shfl_xor(Lk, 2));
        if (k == 0) hs[row] = Lk > 0.0f ? Lk : 0.0f;   // np.maximum(z, 0)
    }
    __syncthreads();

    {
        float z = dot_sse(hs, w2 + t * CMID, CMID);
        // sigmoid: fp32 1/(1+exp(-z)); exp correctly rounded via fp64
        float e = (float)exp((double)(-z));
        ss[t] = __fdiv_rn(1.0f, __fadd_rn(1.0f, e));
    }
    __syncthreads();

    // stable argsort(-s): rank = #{s' > s} + #{equal with smaller index}
    float sc = ss[t];
    int rank = 0;
    for (int c = 0; c < C1; ++c) {
        float v = ss[c];
        rank += (int)((v > sc) || (v == sc && c < t));
    }
    if (rank < C2) g_idx[b * C2 + rank] = t;
}

// ---------------- Kernel 3: per-batch channel gather (plane copy) ----------------
__global__ __launch_bounds__(256) void gather_kernel(const float* __restrict__ x,
                                                     float* __restrict__ out) {
    int bid = blockIdx.x;                      // b*C2 + r
    int b = bid >> 8;
    int c = g_idx[bid];
    const float4* src = (const float4*)(x + ((size_t)(b * C1 + c)) * HW);
    float4* dst = (float4*)(out + (size_t)bid * HW);
    int t = threadIdx.x;
#pragma unroll
    for (int k = 0; k < 4; ++k)
        dst[k * 256 + t] = src[k * 256 + t];
}

extern "C" void kernel_launch(void* const* d_in, const int* in_sizes, int n_in,
                              void* d_out, int out_size, void* d_ws, size_t ws_size,
                              hipStream_t stream) {
    const float* x  = (const float*)d_in[0];
    const float* w1 = (const float*)d_in[1];
    const float* w2 = (const float*)d_in[2];
    float* out = (float*)d_out;

    pool_np_kernel<<<B * C1 / 4, 256, 0, stream>>>(x);
    se_np_kernel<<<B, C1, 0, stream>>>(w1, w2);
    gather_kernel<<<B * C2, 256, 0, stream>>>(x, out);
}

// Round 7
// 101.723 us; speedup vs baseline: 1.1306x; 1.0782x over previous
//
#include <hip/hip_runtime.h>
#include <hip/hip_bf16.h>
#include <math.h>

// x[32,512,64,64] f32; w1[32,512] f32; w2[512,32] f32.
// Bit-replication of the numpy-fp32 reference pipeline (round-4 PASSED, absmax 0.0):
//   y = np.mean(x,(2,3))             -> numpy pairwise_sum (128-blocks, 8 accums, tree)
//   h = relu(np.einsum('bc,rc->br')) -> SSE sum-of-products (mod-4 lanes, (L0+L1)+(L2+L3))
//   s = 1/(1+np.exp(-z))             -> correctly-rounded fp32 exp via fp64, fp32 add/div
//   idx = argsort(-s, stable)[:, :256]; out = take_along_axis(x, idx)
// Round 7: round-6 retry -- nt stores via clang ext_vector_type (float4 struct
// rejected by __builtin_nontemporal_store). Goal: gather's 134 MB write stream
// doesn't evict x from the 256 MB Infinity Cache, so gather reads hit L3.

#define C1 512
#define C2 256
#define CMID 32
#define HW 4096   // 64*64
#define B 32

typedef float f32x4 __attribute__((ext_vector_type(4)));

__device__ float g_y[B * C1];     // pooled means, fp32 (numpy-bit-exact)
__device__ int   g_idx[B * C2];   // top-256 channel indices per batch

// ---------------- Kernel 1: numpy-pairwise mean, one wave per channel ----------------
__global__ __launch_bounds__(256) void pool_np_kernel(const float* __restrict__ x) {
    int bc = blockIdx.x * 4 + (threadIdx.x >> 6);   // channel 0..16383
    int L = threadIdx.x & 63;
    const float* a = x + (size_t)bc * HW;
    const float* base = a + (L >> 1) * 128 + (L & 1) * 4;
    f32x4 r = *(const f32x4*)base;
#pragma unroll
    for (int i = 1; i < 16; ++i) {
        f32x4 v = *(const f32x4*)(base + 8 * i);
        r.x = __fadd_rn(r.x, v.x);
        r.y = __fadd_rn(r.y, v.y);
        r.z = __fadd_rn(r.z, v.z);
        r.w = __fadd_rn(r.w, v.w);
    }
    float s = __fadd_rn(__fadd_rn(r.x, r.y), __fadd_rn(r.z, r.w));
    s = __fadd_rn(s, __shfl_xor(s, 1));    // lane0 chain + lane1 chain
    s = __fadd_rn(s, __shfl_xor(s, 2));    // perfect tree over the 32 blocks
    s = __fadd_rn(s, __shfl_xor(s, 4));
    s = __fadd_rn(s, __shfl_xor(s, 8));
    s = __fadd_rn(s, __shfl_xor(s, 16));
    s = __fadd_rn(s, __shfl_xor(s, 32));
    if (L == 0) g_y[bc] = __fdiv_rn(s, 4096.0f);
}

// numpy einsum SSE sum_of_products_contig_two: single __m128 accumulator;
// per 8-chunk: acc += p[0:4]; acc += p[4:8]; final (L0+L1)+(L2+L3).
__device__ __forceinline__ float dot_sse(const float* __restrict__ u,
                                         const float* __restrict__ v, int n) {
    float L0 = 0.f, L1 = 0.f, L2 = 0.f, L3 = 0.f;
    for (int c = 0; c < n; c += 8) {
        L0 = __fadd_rn(L0, __fmul_rn(u[c+0], v[c+0]));
        L1 = __fadd_rn(L1, __fmul_rn(u[c+1], v[c+1]));
        L2 = __fadd_rn(L2, __fmul_rn(u[c+2], v[c+2]));
        L3 = __fadd_rn(L3, __fmul_rn(u[c+3], v[c+3]));
        L0 = __fadd_rn(L0, __fmul_rn(u[c+4], v[c+4]));
        L1 = __fadd_rn(L1, __fmul_rn(u[c+5], v[c+5]));
        L2 = __fadd_rn(L2, __fmul_rn(u[c+6], v[c+6]));
        L3 = __fadd_rn(L3, __fmul_rn(u[c+7], v[c+7]));
    }
    return __fadd_rn(__fadd_rn(L0, L1), __fadd_rn(L2, L3));
}

// ---------------- Kernel 2: SE MLP (fp32 numpy-replica) + stable rank ----------------
__global__ __launch_bounds__(512) void se_np_kernel(const float* __restrict__ w1,
                                                    const float* __restrict__ w2) {
    int b = blockIdx.x;        // 0..31
    int t = threadIdx.x;       // 0..511
    __shared__ float ys[C1];
    __shared__ float hs[CMID];
    __shared__ float ss[C1];

    ys[t] = g_y[b * C1 + t];
    __syncthreads();

    // Layer 1: 32 rows x 4 independent SSE chains (numpy L0..L3), thread = (row,k)
    if (t < CMID * 4) {
        int row = t >> 2, k = t & 3;
        const float* v = w1 + row * C1;
        float Lk = 0.f;
        for (int c = 0; c < C1; c += 8) {
            Lk = __fadd_rn(Lk, __fmul_rn(ys[c + k],     v[c + k]));
            Lk = __fadd_rn(Lk, __fmul_rn(ys[c + 4 + k], v[c + 4 + k]));
        }
        Lk = __fadd_rn(Lk, __shfl_xor(Lk, 1));   // (L0+L1),(L2+L3)
        Lk = __fadd_rn(Lk, __shfl_xor(Lk, 2));   // final combine
        if (k == 0) hs[row] = Lk > 0.0f ? Lk : 0.0f;   // np.maximum(z, 0)
    }
    __syncthreads();

    {
        float z = dot_sse(hs, w2 + t * CMID, CMID);
        float e = (float)exp((double)(-z));      // correctly-rounded fp32 exp
        ss[t] = __fdiv_rn(1.0f, __fadd_rn(1.0f, e));
    }
    __syncthreads();

    // stable argsort(-s): rank = #{s' > s} + #{equal with smaller index}
    float sc = ss[t];
    int rank = 0;
#pragma unroll 8
    for (int c = 0; c < C1; ++c) {
        float v = ss[c];
        rank += (int)((v > sc) || (v == sc && c < t));
    }
    if (rank < C2) g_idx[b * C2 + rank] = t;
}

// ---------------- Kernel 3: per-batch channel gather (nt stores) ----------------
__global__ __launch_bounds__(256) void gather_kernel(const float* __restrict__ x,
                                                     float* __restrict__ out) {
    int bid = blockIdx.x;                      // b*C2 + r
    int b = bid >> 8;
    int c = g_idx[bid];
    const f32x4* src = (const f32x4*)(x + ((size_t)(b * C1 + c)) * HW);
    f32x4* dst = (f32x4*)(out + (size_t)bid * HW);
    int t = threadIdx.x;
    f32x4 v0 = src[0 * 256 + t];
    f32x4 v1 = src[1 * 256 + t];
    f32x4 v2 = src[2 * 256 + t];
    f32x4 v3 = src[3 * 256 + t];
    __builtin_nontemporal_store(v0, &dst[0 * 256 + t]);
    __builtin_nontemporal_store(v1, &dst[1 * 256 + t]);
    __builtin_nontemporal_store(v2, &dst[2 * 256 + t]);
    __builtin_nontemporal_store(v3, &dst[3 * 256 + t]);
}

extern "C" void kernel_launch(void* const* d_in, const int* in_sizes, int n_in,
                              void* d_out, int out_size, void* d_ws, size_t ws_size,
                              hipStream_t stream) {
    const float* x  = (const float*)d_in[0];
    const float* w1 = (const float*)d_in[1];
    const float* w2 = (const float*)d_in[2];
    float* out = (float*)d_out;

    pool_np_kernel<<<B * C1 / 4, 256, 0, stream>>>(x);
    se_np_kernel<<<B, C1, 0, stream>>>(w1, w2);
    gather_kernel<<<B * C2, 256, 0, stream>>>(x, out);
}

// Round 8
// 100.796 us; speedup vs baseline: 1.1410x; 1.0092x over previous
//
#include <hip/hip_runtime.h>
#include <hip/hip_bf16.h>
#include <math.h>

// x[32,512,64,64] f32; w1[32,512] f32; w2[512,32] f32.
// Bit-replication of the numpy-fp32 reference pipeline (round-4 PASSED, absmax 0.0):
//   y = np.mean(x,(2,3))             -> numpy pairwise_sum (128-blocks, 8 accums, tree)
//   h = relu(np.einsum('bc,rc->br')) -> SSE sum-of-products (mod-4 lanes, (L0+L1)+(L2+L3))
//   s = 1/(1+np.exp(-z))             -> correctly-rounded fp32 exp via fp64, fp32 add/div
//   idx = argsort(-s, stable)[:, :256]; out = take_along_axis(x, idx)
// Round 8: gather split to half-planes (2048 blocks x 256 thr = 524288 threads
// = FULL device residency, was half) for better latency hiding. nt stores kept
// (round-7 win: output stream no longer evicts x from Infinity Cache).

#define C1 512
#define C2 256
#define CMID 32
#define HW 4096   // 64*64
#define B 32

typedef float f32x4 __attribute__((ext_vector_type(4)));

__device__ float g_y[B * C1];     // pooled means, fp32 (numpy-bit-exact)
__device__ int   g_idx[B * C2];   // top-256 channel indices per batch

// ---------------- Kernel 1: numpy-pairwise mean, one wave per channel ----------------
__global__ __launch_bounds__(256) void pool_np_kernel(const float* __restrict__ x) {
    int bc = blockIdx.x * 4 + (threadIdx.x >> 6);   // channel 0..16383
    int L = threadIdx.x & 63;
    const float* a = x + (size_t)bc * HW;
    const float* base = a + (L >> 1) * 128 + (L & 1) * 4;
    f32x4 r = *(const f32x4*)base;
#pragma unroll
    for (int i = 1; i < 16; ++i) {
        f32x4 v = *(const f32x4*)(base + 8 * i);
        r.x = __fadd_rn(r.x, v.x);
        r.y = __fadd_rn(r.y, v.y);
        r.z = __fadd_rn(r.z, v.z);
        r.w = __fadd_rn(r.w, v.w);
    }
    float s = __fadd_rn(__fadd_rn(r.x, r.y), __fadd_rn(r.z, r.w));
    s = __fadd_rn(s, __shfl_xor(s, 1));    // lane0 chain + lane1 chain
    s = __fadd_rn(s, __shfl_xor(s, 2));    // perfect tree over the 32 blocks
    s = __fadd_rn(s, __shfl_xor(s, 4));
    s = __fadd_rn(s, __shfl_xor(s, 8));
    s = __fadd_rn(s, __shfl_xor(s, 16));
    s = __fadd_rn(s, __shfl_xor(s, 32));
    if (L == 0) g_y[bc] = __fdiv_rn(s, 4096.0f);
}

// numpy einsum SSE sum_of_products_contig_two: single __m128 accumulator;
// per 8-chunk: acc += p[0:4]; acc += p[4:8]; final (L0+L1)+(L2+L3).
__device__ __forceinline__ float dot_sse(const float* __restrict__ u,
                                         const float* __restrict__ v, int n) {
    float L0 = 0.f, L1 = 0.f, L2 = 0.f, L3 = 0.f;
    for (int c = 0; c < n; c += 8) {
        L0 = __fadd_rn(L0, __fmul_rn(u[c+0], v[c+0]));
        L1 = __fadd_rn(L1, __fmul_rn(u[c+1], v[c+1]));
        L2 = __fadd_rn(L2, __fmul_rn(u[c+2], v[c+2]));
        L3 = __fadd_rn(L3, __fmul_rn(u[c+3], v[c+3]));
        L0 = __fadd_rn(L0, __fmul_rn(u[c+4], v[c+4]));
        L1 = __fadd_rn(L1, __fmul_rn(u[c+5], v[c+5]));
        L2 = __fadd_rn(L2, __fmul_rn(u[c+6], v[c+6]));
        L3 = __fadd_rn(L3, __fmul_rn(u[c+7], v[c+7]));
    }
    return __fadd_rn(__fadd_rn(L0, L1), __fadd_rn(L2, L3));
}

// ---------------- Kernel 2: SE MLP (fp32 numpy-replica) + stable rank ----------------
__global__ __launch_bounds__(512) void se_np_kernel(const float* __restrict__ w1,
                                                    const float* __restrict__ w2) {
    int b = blockIdx.x;        // 0..31
    int t = threadIdx.x;       // 0..511
    __shared__ float ys[C1];
    __shared__ float hs[CMID];
    __shared__ float ss[C1];

    ys[t] = g_y[b * C1 + t];
    __syncthreads();

    // Layer 1: 32 rows x 4 independent SSE chains (numpy L0..L3), thread = (row,k)
    if (t < CMID * 4) {
        int row = t >> 2, k = t & 3;
        const float* v = w1 + row * C1;
        float Lk = 0.f;
        for (int c = 0; c < C1; c += 8) {
            Lk = __fadd_rn(Lk, __fmul_rn(ys[c + k],     v[c + k]));
            Lk = __fadd_rn(Lk, __fmul_rn(ys[c + 4 + k], v[c + 4 + k]));
        }
        Lk = __fadd_rn(Lk, __shfl_xor(Lk, 1));   // (L0+L1),(L2+L3)
        Lk = __fadd_rn(Lk, __shfl_xor(Lk, 2));   // final combine
        if (k == 0) hs[row] = Lk > 0.0f ? Lk : 0.0f;   // np.maximum(z, 0)
    }
    __syncthreads();

    {
        float z = dot_sse(hs, w2 + t * CMID, CMID);
        float e = (float)exp((double)(-z));      // correctly-rounded fp32 exp
        ss[t] = __fdiv_rn(1.0f, __fadd_rn(1.0f, e));
    }
    __syncthreads();

    // stable argsort(-s): rank = #{s' > s} + #{equal with smaller index}
    float sc = ss[t];
    int rank = 0;
#pragma unroll 8
    for (int c = 0; c < C1; ++c) {
        float v = ss[c];
        rank += (int)((v > sc) || (v == sc && c < t));
    }
    if (rank < C2) g_idx[b * C2 + rank] = t;
}

// ---------------- Kernel 3: gather, half-plane per block (full residency) ----------------
__global__ __launch_bounds__(256) void gather_kernel(const float* __restrict__ x,
                                                     float* __restrict__ out) {
    int bid  = blockIdx.x >> 1;                // plane 0..1023 (b*C2 + r)
    int half = blockIdx.x & 1;                 // 0: first 8 KB, 1: second 8 KB
    int b = bid >> 8;
    int c = g_idx[bid];
    const f32x4* src = (const f32x4*)(x + ((size_t)(b * C1 + c)) * HW);
    f32x4* dst = (f32x4*)(out + (size_t)bid * HW);
    int j = half * 512 + threadIdx.x;          // float4 index within plane
    f32x4 v0 = src[j];
    f32x4 v1 = src[j + 256];
    __builtin_nontemporal_store(v0, &dst[j]);
    __builtin_nontemporal_store(v1, &dst[j + 256]);
}

extern "C" void kernel_launch(void* const* d_in, const int* in_sizes, int n_in,
                              void* d_out, int out_size, void* d_ws, size_t ws_size,
                              hipStream_t stream) {
    const float* x  = (const float*)d_in[0];
    const float* w1 = (const float*)d_in[1];
    const float* w2 = (const float*)d_in[2];
    float* out = (float*)d_out;

    pool_np_kernel<<<B * C1 / 4, 256, 0, stream>>>(x);
    se_np_kernel<<<B, C1, 0, stream>>>(w1, w2);
    gather_kernel<<<B * C2 * 2, 256, 0, stream>>>(x, out);
}